// Round 2
// baseline (186.609 us; speedup 1.0000x reference)
//
#include <hip/hip_runtime.h>
#include <hip/hip_fp16.h>

// Tree NN: reps = emb[tokens] (4096 x 128 x 128); 7x: reps = tanh(concat(pairs) @ W_tree^T + b);
// out = root @ W_cls^T + b_cls.
//
// R15: occupancy attack. R14's register prefetch SPILLED (WRITE_SIZE 96KB->10.8MB scratch
// signature, VGPR stuck at 84) and was neutral. Real limiter: 12 waves/CU (LDS 53KB -> 3
// blocks/CU of 256 threads = 3 waves/SIMD) on a latency-bound 14-barrier chain.
//  1. 512-THREAD BLOCKS, 8 WAVES, ONE n-tile per wave (Wf[8] = 32 VGPR, half of R14).
//     LDS unchanged (53KB) -> still 3 blocks/CU, but 24 waves/CU = 6 waves/SIMD: 2x TLP.
//     __launch_bounds__(512,6) caps VGPR at ~85 (512-reg SIMD pool / 6 waves).
//     Cost accepted: per-wave A-reads unchanged but 8 waves -> 2x total LDS read traffic
//     (~35% LDS-pipe busy at target wall).
//  2. DROPPED the register embedding prefetch (it spilled; gather latency now hidden by
//     TLP instead). Kept R14's raw barriers (lgkmcnt-only, no vmcnt drain -> token
//     preloads stay in flight) and K-split 2x4 MFMA chains + bias-in-accumulator.
// Kept: pair-contig LDS layout, conflict-free gather writes, fp16 MFMA 16x16x32,
// fp32 accumulate/tanh/classifier, grid 768 (3 blocks/CU), batched L5/L6 tail.
//
// Wave w owns output n-tile w (features [16w,16w+16)) at every level. Activations in LDS,
// pair-contiguous so concat(left,right) is free. Per-sample gather,L0..L4 (stash L4-out
// in bufC); batched tail L5,L6+classifier per pair.

typedef _Float16 half8 __attribute__((ext_vector_type(8)));
typedef float floatx4 __attribute__((ext_vector_type(4)));

#define STRIDE 264   // 256 + 8 fp16 pad: A-row ds_read_b128 conflict-free
#define UROW   33    // uint4 per row
#define NPAIR  2048

// Raw workgroup barrier: orders LDS ops (lgkmcnt(0) + memory clobber pins IR-level order;
// sched_barrier pins codegen scheduling) but does NOT drain vmcnt -> token preloads stay
// in flight across levels. All 512 threads hit every bar().
__device__ __forceinline__ void bar() {
  asm volatile("s_waitcnt lgkmcnt(0)" ::: "memory");
  __builtin_amdgcn_sched_barrier(0);
  __builtin_amdgcn_s_barrier();
  __builtin_amdgcn_sched_barrier(0);
}

__device__ __forceinline__ float fast_tanh(float x) {
  // No clamp needed: e=inf -> 1; e=0 -> -1. Inputs never NaN.
  float e = __expf(2.f * x);
  return 1.f - 2.f * __builtin_amdgcn_rcpf(e + 1.f);
}

__device__ __forceinline__ unsigned pkrtz(float a, float b) {
  auto h = __builtin_amdgcn_cvt_pkrtz(a, b);   // __fp16 ext_vector(2)
  return __builtin_bit_cast(unsigned, h);
}

// Gather, 512 threads: thread (row=t&63, seg=t>>6) covers leaf 2*row+(seg>>2),
// feature-quarter q=seg&3 (32 floats). LDS row r = pair (2r,2r+1) concatenated:
// leaf-half lb at fp16 [lb*128, lb*128+128). Writes 4 uint4 at row*33 + lb*16 + q*4:
// consecutive lanes hit consecutive rows (stride 33 uint4 = 4 banks/lane, 2-way per
// 16-lane phase) -> conflict-free.
__device__ __forceinline__ void gather_quarter(int tok, const float* __restrict__ emb,
                                               _Float16* buf, int row, int lb, int q) {
  const float4* src = (const float4*)emb + (size_t)tok * 32 + q * 8;
  uint4* dst = (uint4*)buf + row * UROW + lb * 16 + q * 4;
  float4 x[8];
#pragma unroll
  for (int j = 0; j < 8; ++j) x[j] = src[j];
#pragma unroll
  for (int j = 0; j < 4; ++j) {
    float4 a = x[2 * j], b = x[2 * j + 1];
    uint4 w;
    w.x = pkrtz(a.x, a.y); w.y = pkrtz(a.z, a.w);
    w.z = pkrtz(b.x, b.y); w.w = pkrtz(b.z, b.w);
    dst[j] = w;
  }
}

// K=256 MFMA for one 16-row m-tile, ONE n-tile, K-split into 2 independent 4-chains.
// Chain A initialized with bias (per-col, uniform across the 4 D-rows of a reg quad).
// A-frag: A[m=lane&15][k=quad*8+j]; B-frag: B[k=quad*8+j][n=lane&15];
// D: col=lane&15, row=quad*4+reg (verified layouts, learn_hip m89/m91).
__device__ __forceinline__ floatx4 mfma_k256(const _Float16* arow, const half8 (&Wf)[8],
                                             float bias) {
  floatx4 aA = (floatx4){bias, bias, bias, bias};
  floatx4 aB = (floatx4){0.f, 0.f, 0.f, 0.f};
#pragma unroll
  for (int ks = 0; ks < 4; ++ks) {
    half8 x0 = *(const half8*)(arow + ks * 32);
    half8 x1 = *(const half8*)(arow + (ks + 4) * 32);
    aA = __builtin_amdgcn_mfma_f32_16x16x32_f16(x0, Wf[ks],     aA, 0, 0, 0);
    aB = __builtin_amdgcn_mfma_f32_16x16x32_f16(x1, Wf[ks + 4], aB, 0, 0, 0);
  }
  return aA + aB;
}

// One wave: its n-tile for MT m-tiles; pair-contiguous store, MOUT row mask.
// Stale rows above MOUT always hold finite tanh/leaf values; masked at store.
template<int MT, int MOUT>
__device__ __forceinline__ void level_std(
    const _Float16* inb, _Float16* outb,
    const half8 (&Wf)[8], float bias, int col, int l15, int quad)
{
  floatx4 acc[MT];
#pragma unroll
  for (int m = 0; m < MT; ++m)
    acc[m] = mfma_k256(inb + (m * 16 + l15) * STRIDE + quad * 8, Wf, bias);

  const int mrow = quad * 4;
#pragma unroll
  for (int m = 0; m < MT; ++m)
#pragma unroll
    for (int r = 0; r < 4; ++r) {
      const int node = m * 16 + mrow + r;
      if (node < MOUT) {
        float v = fast_tanh(acc[m][r]);
        outb[(node >> 1) * STRIDE + (node & 1) * 128 + col] = (_Float16)v;
      }
    }
}

__global__ __launch_bounds__(512, 6)   // 8 waves/block; 6 waves/SIMD -> VGPR cap ~85
void tree_kernel(const int* __restrict__ tokens,
                 const float* __restrict__ embedding,
                 const float* __restrict__ W_tree,
                 const float* __restrict__ b_tree,
                 const float* __restrict__ W_cls,
                 const float* __restrict__ b_cls,
                 float* __restrict__ out)
{
  __shared__ __align__(16) _Float16 bufA[64 * STRIDE];   // leaves / even outputs (33.8 KB)
  __shared__ __align__(16) _Float16 bufB[32 * STRIDE];   // odd outputs (16.9 KB)
  __shared__ __align__(16) _Float16 bufC[4 * STRIDE];    // pair stash: L4 outs (2.1 KB)
  __shared__ float wavepart[8][2][3];                    // classifier partials (192 B)

  const int tid  = threadIdx.x;
  const int wid  = tid >> 6;               // wave id 0-7 = n-tile id
  const int lane = tid & 63;
  const int l15  = lane & 15;
  const int quad = lane >> 4;
  const int col  = wid * 16 + l15;         // this lane's output feature column
  const int row  = tid & 63;               // gather destination row
  const int seg  = tid >> 6;               // gather segment 0-7
  const int lb   = seg >> 2;               // leaf-of-pair bit
  const int q    = seg & 3;                // feature quarter
  const int tidx = 2 * row + lb;           // this thread's token index within a sample

  // ---- stage this wave's n-tile of W_tree as B-fragments (32 VGPR) ----
  // B[k][n] = W_tree[e=n][h=k]  (einsum 'bnh,eh->bne' => out = comb @ W^T)
  half8 Wf[8];
#pragma unroll
  for (int ks = 0; ks < 8; ++ks) {
    const int k = ks * 32 + quad * 8;
    const float4* p = (const float4*)(W_tree + col * 256 + k);
    float4 lo = p[0], hi = p[1];
    half8 f;
    f[0] = (_Float16)lo.x; f[1] = (_Float16)lo.y; f[2] = (_Float16)lo.z; f[3] = (_Float16)lo.w;
    f[4] = (_Float16)hi.x; f[5] = (_Float16)hi.y; f[6] = (_Float16)hi.z; f[7] = (_Float16)hi.w;
    Wf[ks] = f;
  }
  const float bias = b_tree[col];

  // classifier weights for this lane's column: loop-invariant (3 VGPR)
  float wc[3];
#pragma unroll
  for (int o = 0; o < 3; ++o) wc[o] = W_cls[o * 128 + col];

  int tokA = tokens[(2 * blockIdx.x) * 128 + tidx];       // preloaded pair tokens
  int tokB = tokens[(2 * blockIdx.x + 1) * 128 + tidx];

#pragma unroll 1
  for (int p = blockIdx.x; p < NPAIR; p += gridDim.x) {
    int pn = p + gridDim.x;
    if (pn >= NPAIR) pn = p;               // last iteration: harmless self-reload

    // ---- s0 gather (token preloaded) + preload next-pair tokens ----
    gather_quarter(tokA, embedding, bufA, row, lb, q);
    const int tokAn = tokens[(2 * pn) * 128 + tidx];
    const int tokBn = tokens[(2 * pn + 1) * 128 + tidx];
    bar();

    // ---- s0 levels: L0..L4, stash L4-out in bufC rows 0-1 ----
    level_std<4, 64>(bufA, bufB, Wf, bias, col, l15, quad);   // L0
    bar();
    level_std<2, 32>(bufB, bufA, Wf, bias, col, l15, quad);   // L1
    bar();
    level_std<1, 16>(bufA, bufB, Wf, bias, col, l15, quad);   // L2
    bar();
    level_std<1,  8>(bufB, bufA, Wf, bias, col, l15, quad);   // L3
    bar();
    level_std<1,  4>(bufA, bufC, Wf, bias, col, l15, quad);   // L4 -> bufC rows 0-1
    bar();

    // ---- s1 gather ----
    gather_quarter(tokB, embedding, bufA, row, lb, q);
    bar();

    // ---- s1 levels: L0..L4, stash L4-out in bufC rows 2-3 ----
    level_std<4, 64>(bufA, bufB, Wf, bias, col, l15, quad);   // L0
    bar();
    level_std<2, 32>(bufB, bufA, Wf, bias, col, l15, quad);   // L1
    bar();
    level_std<1, 16>(bufA, bufB, Wf, bias, col, l15, quad);   // L2
    bar();
    level_std<1,  8>(bufB, bufA, Wf, bias, col, l15, quad);   // L3
    bar();
    level_std<1,  4>(bufA, bufC + 2 * STRIDE, Wf, bias, col, l15, quad); // L4 -> rows 2-3
    bar();

    // ---- batched L5: bufC rows 0-3 -> bufA rows 0-1 ----
    {
      const int rclamp = l15 < 4 ? l15 : 3;          // bufC bounds; rows>=4 discarded
      floatx4 acc = mfma_k256(bufC + rclamp * STRIDE + quad * 8, Wf, bias);
      const int mrow = quad * 4;
#pragma unroll
      for (int r = 0; r < 4; ++r) {
        const int mr = mrow + r;                     // mr<4 valid: sample mr>>1, node mr&1
        if (mr < 4) {
          float v = fast_tanh(acc[r]);
          bufA[(mr >> 1) * STRIDE + (mr & 1) * 128 + col] = (_Float16)v;
        }
      }
    }
    bar();

    // ---- batched L6 + classifier partials from registers ----
    {
      floatx4 acc = mfma_k256(bufA + l15 * STRIDE + quad * 8, Wf, bias); // rows 0-1 = roots
      float part[2][3] = {{0.f, 0.f, 0.f}, {0.f, 0.f, 0.f}};
      if (quad == 0) {
#pragma unroll
        for (int rr = 0; rr < 2; ++rr) {             // rr = sample
          float v = fast_tanh(acc[rr]);
#pragma unroll
          for (int o = 0; o < 3; ++o) part[rr][o] = fmaf(v, wc[o], part[rr][o]);
        }
      }
#pragma unroll
      for (int rr = 0; rr < 2; ++rr) {
#pragma unroll
        for (int o = 0; o < 3; ++o) {
          float v = part[rr][o];                     // nonzero only in quad-0 lanes
          v += __shfl_down(v, 8);
          v += __shfl_down(v, 4);
          v += __shfl_down(v, 2);
          v += __shfl_down(v, 1);
          if (lane == 0) wavepart[wid][rr][o] = v;
        }
      }
    }
    bar();
    if (tid < 6) {
      const int rr = tid / 3, o = tid - 3 * rr;
      float v = 0.f;
#pragma unroll
      for (int w = 0; w < 8; ++w) v += wavepart[w][rr][o];
      out[(2 * p + rr) * 3 + o] = v + b_cls[o];
    }
    tokA = tokAn; tokB = tokBn;
    // next pair's gather overwrites bufA: all L6 bufA reads completed before the wavepart
    // barrier; wavepart next written 14 barriers later -> safe.
  }
}

extern "C" void kernel_launch(void* const* d_in, const int* in_sizes, int n_in,
                              void* d_out, int out_size, void* d_ws, size_t ws_size,
                              hipStream_t stream) {
  const int*   tokens    = (const int*)d_in[0];
  const float* embedding = (const float*)d_in[1];
  const float* W_tree    = (const float*)d_in[2];
  const float* b_tree    = (const float*)d_in[3];
  const float* W_cls     = (const float*)d_in[4];
  const float* b_cls     = (const float*)d_in[5];
  float* out = (float*)d_out;

  dim3 grid(768), block(512);   // 3 blocks/CU x 256 CUs (LDS-limited); 24 waves/CU
  tree_kernel<<<grid, block, 0, stream>>>(tokens, embedding, W_tree, b_tree, W_cls, b_cls, out);
}